// Round 3
// baseline (182.977 us; speedup 1.0000x reference)
//
#include <hip/hip_runtime.h>

// AttentionFlow: B=8, N=50000, D=32, N_SRC=12500, DEG=8, R=500, E=800000.
// Segments = exactly 8 consecutive edges (idx_vi == e>>3).
//
// One 64-lane wave handles NSEG=4 segments (32 edges), software-pipelined:
// all headers -> all gathers (16 float4/lane in flight) -> compute -> coalesced
// epilogue. Lane layout per segment: k=lane>>3 (edge), q=lane&7 (dim quad).
// XCD-chunked block swizzle keeps each batch's atomics on one XCD's L2.

#define DDIM 32
#define NSEG 4

__global__ __launch_bounds__(256) void attn_flow_kernel(
    const float* __restrict__ node_attention,   // B*N
    const float* __restrict__ hidden_con,       // B*N*D
    const float* __restrict__ hidden_uncon,     // N*D
    const float* __restrict__ edges_y,          // E
    const float* __restrict__ rel_emb,          // R*D
    const float* __restrict__ ws,               // 4*D
    const float* __restrict__ bvec,             // D
    const float* __restrict__ out_w,            // D
    const int*   __restrict__ edges,            // E*6
    float* __restrict__ trans_attention,        // E
    float* __restrict__ new_node_attention,     // B*N
    int n_groups, int N_nodes, int nwg)
{
    // bijective XCD-chunked swizzle (works for any nwg)
    const int q8 = nwg >> 3, r8 = nwg & 7;
    const int xcd = blockIdx.x & 7, ii = blockIdx.x >> 3;
    const int swz = (xcd < r8 ? xcd * (q8 + 1) : r8 * (q8 + 1) + (xcd - r8) * q8) + ii;

    const int wid  = threadIdx.x >> 6;
    const int lane = threadIdx.x & 63;
    const int gid0 = (swz * 4 + wid) * NSEG;   // first segment of this wave
    if (gid0 >= n_groups) return;
    const int k = lane >> 3;   // edge within segment
    const int q = lane & 7;    // dim quad

    // ---- phase 1: headers (independent int2 loads) ----
    int idx_[NSEG], vi_[NSEG], vj_[NSEG], rel_[NSEG];
#pragma unroll
    for (int s = 0; s < NSEG; ++s) {
        long g = gid0 + s; if (g >= n_groups) g = n_groups - 1;  // safe clamp
        const int2 h  = *(const int2*)(edges + g * 48);          // idx, vi (uniform)
        const int2 vr = *(const int2*)(edges + (g * 8 + k) * 6 + 2); // vj, rel
        idx_[s] = h.x; vi_[s] = h.y; vj_[s] = vr.x; rel_[s] = vr.y;
    }

    // ---- phase 2: all gathers in flight ----
    float4 hvi_[NSEG], hvj_[NSEG], huj_[NSEG], re_[NSEG];
    float  na_[NSEG];
#pragma unroll
    for (int s = 0; s < NSEG; ++s) {
        const long bc = (long)idx_[s] * N_nodes;
        hvi_[s] = ((const float4*)(hidden_con + (bc + vi_[s]) * DDIM))[q];
        hvj_[s] = ((const float4*)(hidden_con + (bc + vj_[s]) * DDIM))[q];
        huj_[s] = ((const float4*)(hidden_uncon + (long)vj_[s] * DDIM))[q];
        re_[s]  = ((const float4*)(rel_emb + (long)rel_[s] * DDIM))[q];
        na_[s]  = node_attention[bc + vi_[s]];   // uniform -> broadcast
    }

    // weights (L1-resident; out_b dropped: constant per segment, cancels in softmax)
    const float4 w0 = ((const float4*)(ws          ))[q];
    const float4 w1 = ((const float4*)(ws +   DDIM))[q];
    const float4 w2 = ((const float4*)(ws + 2*DDIM))[q];
    const float4 w3 = ((const float4*)(ws + 3*DDIM))[q];
    const float4 bb = ((const float4*)(bvec ))[q];
    const float4 ow = ((const float4*)(out_w))[q];

    // ---- phase 3: compute ----
    float t_[NSEG];
#pragma unroll
    for (int s = 0; s < NSEG; ++s) {
        const float4 a = hvi_[s], c = hvj_[s], u = huj_[s], r = re_[s];
        float h0 = a.x * (c.x * fmaf(r.x, w1.x, w0.x) + u.x * fmaf(r.x, w3.x, w2.x)) + bb.x;
        float h1 = a.y * (c.y * fmaf(r.y, w1.y, w0.y) + u.y * fmaf(r.y, w3.y, w2.y)) + bb.y;
        float h2 = a.z * (c.z * fmaf(r.z, w1.z, w0.z) + u.z * fmaf(r.z, w3.z, w2.z)) + bb.z;
        float h3 = a.w * (c.w * fmaf(r.w, w1.w, w0.w) + u.w * fmaf(r.w, w3.w, w2.w)) + bb.w;
        float p = fmaxf(h0, 0.f) * ow.x + fmaxf(h1, 0.f) * ow.y
                + fmaxf(h2, 0.f) * ow.z + fmaxf(h3, 0.f) * ow.w;
        // dot-reduce over dim quads (lanes xor 1,2,4)
        p += __shfl_xor(p, 1, 64);
        p += __shfl_xor(p, 2, 64);
        p += __shfl_xor(p, 4, 64);
        // segment softmax over the 8 edges (lanes xor 8,16,32)
        float m = p;
        m = fmaxf(m, __shfl_xor(m, 8, 64));
        m = fmaxf(m, __shfl_xor(m, 16, 64));
        m = fmaxf(m, __shfl_xor(m, 32, 64));
        const float ex = expf(p - m);
        float sd = ex;
        sd += __shfl_xor(sd, 8, 64);
        sd += __shfl_xor(sd, 16, 64);
        sd += __shfl_xor(sd, 32, 64);
        t_[s] = ex / sd;
    }

    // ---- phase 4: coalesced epilogue (lanes 0..31 own the 32 edges in order) ----
    // shuffles done with all lanes active
    const int src = (lane & 7) * 8;          // lane holding edge (lane&7) of each segment
    const float ts0 = __shfl(t_[0], src, 64), ts1 = __shfl(t_[1], src, 64),
                ts2 = __shfl(t_[2], src, 64), ts3 = __shfl(t_[3], src, 64);
    const int  vjs0 = __shfl(vj_[0], src, 64), vjs1 = __shfl(vj_[1], src, 64),
               vjs2 = __shfl(vj_[2], src, 64), vjs3 = __shfl(vj_[3], src, 64);

    if (lane < 32) {
        const int ss = lane >> 3;            // segment this lane writes
        const float tsel  = ss == 0 ? ts0 : ss == 1 ? ts1 : ss == 2 ? ts2 : ts3;
        const int   vjsel = ss == 0 ? vjs0 : ss == 1 ? vjs1 : ss == 2 ? vjs2 : vjs3;
        const float nasel = ss == 0 ? na_[0] : ss == 1 ? na_[1] : ss == 2 ? na_[2] : na_[3];
        const int  idxsel = ss == 0 ? idx_[0] : ss == 1 ? idx_[1] : ss == 2 ? idx_[2] : idx_[3];
        const long e = (long)gid0 * 8 + lane;
        if (e < (long)n_groups * 8) {
            const float ta = nasel * tsel * edges_y[e];
            trans_attention[e] = ta;         // coalesced 128B per wave
            atomicAdd(new_node_attention + (long)idxsel * N_nodes + vjsel, ta);
        }
    }
}

extern "C" void kernel_launch(void* const* d_in, const int* in_sizes, int n_in,
                              void* d_out, int out_size, void* d_ws, size_t ws_size,
                              hipStream_t stream) {
    const float* node_attention = (const float*)d_in[0];
    const float* hidden_con    = (const float*)d_in[1];
    const float* hidden_uncon  = (const float*)d_in[2];
    const float* edges_y       = (const float*)d_in[3];
    const float* rel_emb       = (const float*)d_in[4];
    const float* ws            = (const float*)d_in[5];
    const float* bvec          = (const float*)d_in[6];
    const float* out_w         = (const float*)d_in[7];
    const int*   edges         = (const int*)d_in[9];

    const int E        = in_sizes[9] / 6;     // 800000
    const int BN       = in_sizes[0];         // 400000
    const int N_nodes  = in_sizes[2] / DDIM;  // 50000
    const int n_groups = E / 8;               // 100000

    float* trans_attention    = (float*)d_out;
    float* new_node_attention = (float*)d_out + E;

    hipMemsetAsync(new_node_attention, 0, (size_t)BN * sizeof(float), stream);

    const int n_waves = (n_groups + NSEG - 1) / NSEG;   // 25000
    const int blocks  = (n_waves + 3) / 4;              // 6250 (4 waves/block)
    attn_flow_kernel<<<blocks, 256, 0, stream>>>(
        node_attention, hidden_con, hidden_uncon, edges_y, rel_emb,
        ws, bvec, out_w, edges,
        trans_attention, new_node_attention, n_groups, N_nodes, blocks);
}

// Round 4
// 170.278 us; speedup vs baseline: 1.0746x; 1.0746x over previous
//
#include <hip/hip_runtime.h>

// AttentionFlow: B=8, N=50000, D=32, DEG=8, E=800000; segments = 8 consecutive edges.
// One 64-lane wave handles 4 segments. Lane layout: k=lane>>3 (edge), q=lane&7 (dim quad).
// All 20 gather loads are issued as NAMED float4s before any use, with
// __launch_bounds__(256,4) (VGPR cap 128) so the compiler keeps them in flight.
// This attacks the round-1 latency bound (duty cycle ~4%/wave, occupancy-capped).

#define DDIM 32

__global__ __launch_bounds__(256, 4) void attn_flow_kernel(
    const float* __restrict__ node_attention,   // B*N
    const float* __restrict__ hidden_con,       // B*N*D
    const float* __restrict__ hidden_uncon,     // N*D
    const float* __restrict__ edges_y,          // E
    const float* __restrict__ rel_emb,          // R*D
    const float* __restrict__ ws,               // 4*D
    const float* __restrict__ bvec,             // D
    const float* __restrict__ out_w,            // D
    const int*   __restrict__ edges,            // E*6 (idx,vi,vj,rel,idx_vi,key)
    float* __restrict__ trans_attention,        // E
    float* __restrict__ new_node_attention,     // B*N
    int n_groups, int N_nodes)
{
    const int wave = (int)((blockIdx.x * 256u + threadIdx.x) >> 6);
    const int gid0 = wave * 4;
    if (gid0 >= n_groups) return;
    const int lane = (int)(threadIdx.x & 63);
    const int k = lane >> 3;   // edge within segment
    const int q = lane & 7;    // dim quad

    // per-q weights (tiny, cache-resident; out_b dropped — constant per segment,
    // cancels in the segment softmax)
    const float4 w0 = ((const float4*)(ws          ))[q];
    const float4 w1 = ((const float4*)(ws +   DDIM))[q];
    const float4 w2 = ((const float4*)(ws + 2*DDIM))[q];
    const float4 w3 = ((const float4*)(ws + 3*DDIM))[q];
    const float4 bb = ((const float4*)(bvec ))[q];
    const float4 ow = ((const float4*)(out_w))[q];

    // ---- phase 1: headers for 4 segments, issued back-to-back ----
    // h*: (idx, vi) uniform per segment; p*: (vj, rel) per edge k
    const int2 h0 = *(const int2*)(edges + (long)(gid0 + 0) * 48);
    const int2 h1 = *(const int2*)(edges + (long)(gid0 + 1) * 48);
    const int2 h2 = *(const int2*)(edges + (long)(gid0 + 2) * 48);
    const int2 h3 = *(const int2*)(edges + (long)(gid0 + 3) * 48);
    const int2 p0 = *(const int2*)(edges + ((long)(gid0 + 0) * 8 + k) * 6 + 2);
    const int2 p1 = *(const int2*)(edges + ((long)(gid0 + 1) * 8 + k) * 6 + 2);
    const int2 p2 = *(const int2*)(edges + ((long)(gid0 + 2) * 8 + k) * 6 + 2);
    const int2 p3 = *(const int2*)(edges + ((long)(gid0 + 3) * 8 + k) * 6 + 2);

    const long bc0 = (long)h0.x * N_nodes;
    const long bc1 = (long)h1.x * N_nodes;
    const long bc2 = (long)h2.x * N_nodes;
    const long bc3 = (long)h3.x * N_nodes;

    // ---- phase 2: all 20 gather loads in flight (named, no arrays) ----
#define GATHER(s)                                                                       \
    const float4 a##s = ((const float4*)(hidden_con + (bc##s + h##s.y) * DDIM))[q];     \
    const float4 c##s = ((const float4*)(hidden_con + (bc##s + p##s.x) * DDIM))[q];     \
    const float4 u##s = ((const float4*)(hidden_uncon + (long)p##s.x * DDIM))[q];       \
    const float4 r##s = ((const float4*)(rel_emb + (long)p##s.y * DDIM))[q];            \
    const float na##s = node_attention[bc##s + h##s.y];
    GATHER(0) GATHER(1) GATHER(2) GATHER(3)
#undef GATHER

    // ---- phase 3+4: compute + epilogue per segment (frees registers early) ----
#define COMP(s)                                                                         \
    {                                                                                   \
        float x0 = a##s.x * (c##s.x * fmaf(r##s.x, w1.x, w0.x)                          \
                           + u##s.x * fmaf(r##s.x, w3.x, w2.x)) + bb.x;                 \
        float x1 = a##s.y * (c##s.y * fmaf(r##s.y, w1.y, w0.y)                          \
                           + u##s.y * fmaf(r##s.y, w3.y, w2.y)) + bb.y;                 \
        float x2 = a##s.z * (c##s.z * fmaf(r##s.z, w1.z, w0.z)                          \
                           + u##s.z * fmaf(r##s.z, w3.z, w2.z)) + bb.z;                 \
        float x3 = a##s.w * (c##s.w * fmaf(r##s.w, w1.w, w0.w)                          \
                           + u##s.w * fmaf(r##s.w, w3.w, w2.w)) + bb.w;                 \
        float pp = fmaxf(x0, 0.f) * ow.x + fmaxf(x1, 0.f) * ow.y                        \
                 + fmaxf(x2, 0.f) * ow.z + fmaxf(x3, 0.f) * ow.w;                       \
        pp += __shfl_xor(pp, 1, 64);                                                    \
        pp += __shfl_xor(pp, 2, 64);                                                    \
        pp += __shfl_xor(pp, 4, 64);                                                    \
        float mm = pp;                                                                  \
        mm = fmaxf(mm, __shfl_xor(mm, 8, 64));                                          \
        mm = fmaxf(mm, __shfl_xor(mm, 16, 64));                                         \
        mm = fmaxf(mm, __shfl_xor(mm, 32, 64));                                         \
        const float ex = expf(pp - mm);                                                 \
        float sd = ex;                                                                  \
        sd += __shfl_xor(sd, 8, 64);                                                    \
        sd += __shfl_xor(sd, 16, 64);                                                   \
        sd += __shfl_xor(sd, 32, 64);                                                   \
        const float tr = ex / sd;                                                       \
        if (q == 0) {                                                                   \
            const long e = (long)(gid0 + s) * 8 + k;                                    \
            const float ta = na##s * tr * edges_y[e];                                   \
            trans_attention[e] = ta;                                                    \
            atomicAdd(new_node_attention + bc##s + p##s.x, ta);                         \
        }                                                                               \
    }
    COMP(0) COMP(1) COMP(2) COMP(3)
#undef COMP
}

extern "C" void kernel_launch(void* const* d_in, const int* in_sizes, int n_in,
                              void* d_out, int out_size, void* d_ws, size_t ws_size,
                              hipStream_t stream) {
    const float* node_attention = (const float*)d_in[0];
    const float* hidden_con    = (const float*)d_in[1];
    const float* hidden_uncon  = (const float*)d_in[2];
    const float* edges_y       = (const float*)d_in[3];
    const float* rel_emb       = (const float*)d_in[4];
    const float* ws            = (const float*)d_in[5];
    const float* bvec          = (const float*)d_in[6];
    const float* out_w         = (const float*)d_in[7];
    const int*   edges         = (const int*)d_in[9];

    const int E        = in_sizes[9] / 6;     // 800000
    const int BN       = in_sizes[0];         // 400000
    const int N_nodes  = in_sizes[2] / DDIM;  // 50000
    const int n_groups = E / 8;               // 100000

    float* trans_attention    = (float*)d_out;
    float* new_node_attention = (float*)d_out + E;

    // d_out is poisoned 0xAA before every timed launch -> zero the scatter target.
    hipMemsetAsync(new_node_attention, 0, (size_t)BN * sizeof(float), stream);

    const int n_waves = (n_groups + 3) / 4;   // 25000
    const int blocks  = (n_waves + 3) / 4;    // 6250 (4 waves/block)
    attn_flow_kernel<<<blocks, 256, 0, stream>>>(
        node_attention, hidden_con, hidden_uncon, edges_y, rel_emb,
        ws, bvec, out_w, edges,
        trans_attention, new_node_attention, n_groups, N_nodes);
}